// Round 1
// baseline (21874.438 us; speedup 1.0000x reference)
//
#include <hip/hip_runtime.h>
#include <hip/hip_fp16.h>

constexpr int kB = 128;
constexpr int kN = 1000;
constexpr int kE = 128;
constexpr int kH = 8;
constexpr float kFP8Scale = 64.f;         // fp8 values stored as v*64
constexpr float kQKScale = 0.25f / 64.f;  // 1/sqrt(16) folded with 1/64

typedef _Float16 h2 __attribute__((ext_vector_type(2)));
typedef float f2 __attribute__((ext_vector_type(2)));

__device__ __forceinline__ h2 pkrtz(float a, float b) {
  return __builtin_bit_cast(h2, __builtin_amdgcn_cvt_pkrtz(a, b));
}

// dot of 4 fp8 elems (packed in u, stored value*64) against 4 f16 elems.
__device__ __forceinline__ float dotq(unsigned u, h2 qa, h2 qb, float s) {
  f2 lo = __builtin_amdgcn_cvt_pk_f32_fp8(u, false);
  f2 hi = __builtin_amdgcn_cvt_pk_f32_fp8(u, true);
  h2 l16 = pkrtz(lo.x, lo.y);
  h2 h16 = pkrtz(hi.x, hi.y);
  s = __builtin_amdgcn_fdot2(l16, qa, s, false);
  s = __builtin_amdgcn_fdot2(h16, qb, s, false);
  return s;
}
// 16-elem fp8 dot (one uint4) against 16 f16 elems in q8[0..7].
__device__ __forceinline__ float dot16(uint4 tq, const h2* q8, float s) {
  s = dotq(tq.x, q8[0], q8[1], s);
  s = dotq(tq.y, q8[2], q8[3], s);
  s = dotq(tq.z, q8[4], q8[5], s);
  s = dotq(tq.w, q8[6], q8[7], s);
  return s;
}

__device__ __forceinline__ float fast_tanh(float x) {
  float t = __expf(2.f * x);
  return 1.f - 2.f / (t + 1.f);
}

__device__ __forceinline__ unsigned char enc_fp8(float v) {
  unsigned p = __builtin_amdgcn_cvt_pk_fp8_f32(v, v, 0, false);
  return (unsigned char)(p & 0xFF);
}

// online-softmax / argmax combine; tie -> smaller node id (jnp.argmax).
__device__ __forceinline__ void combine(float& m, float& s, int& a,
                                        float mo, float so, int ao) {
  bool take = (mo > m) || (mo == m && ao < a);
  float mw = take ? mo : m;
  float ml = take ? m : mo;
  float sw = take ? so : s;
  float sl = take ? s : so;
  s = sw + sl * __expf(ml - mw);
  m = mw;
  a = take ? ao : a;
}

// LDS-only barrier: drains DS ops, leaves global register-loads in flight
// (a plain __syncthreads would insert s_waitcnt vmcnt(0) and kill the
// cross-barrier prefetch of lu/q rows).
__device__ __forceinline__ void barrier_lds() {
  asm volatile("s_waitcnt lgkmcnt(0)" ::: "memory");
  __builtin_amdgcn_s_barrier();
  asm volatile("" ::: "memory");
}

// ---------------------------------------------------------------------------
// Kernel A: qkv projection -> fp8 (value*64) k / v / logit_k.
// ---------------------------------------------------------------------------
__global__ __launch_bounds__(384) void qkv_kernel(
    const float* __restrict__ ne, const float* __restrict__ Wqkv,
    const float* __restrict__ bqkv, unsigned char* __restrict__ kq,
    unsigned char* __restrict__ vq, unsigned char* __restrict__ lkq) {
  __shared__ float rows[16 * kE];
  int b = blockIdx.x;
  int n0 = blockIdx.y * 16;
  int ntile = min(16, kN - n0);
  int tid = threadIdx.x;

  for (int idx = tid; idx < ntile * kE; idx += 384)
    rows[idx] = ne[(b * kN + n0) * kE + idx];
  __syncthreads();

  int j = tid;  // 0..383
  float acc[16];
#pragma unroll
  for (int r = 0; r < 16; ++r) acc[r] = 0.f;
  for (int i = 0; i < kE; ++i) {
    float w = Wqkv[i * (3 * kE) + j];
#pragma unroll
    for (int r = 0; r < 16; ++r) acc[r] += rows[r * kE + i] * w;
  }
  float bias = bqkv[j];
  unsigned char* dst;
  int col;
  if (j < kE) { dst = kq; col = j; }
  else if (j < 2 * kE) { dst = vq; col = j - kE; }
  else { dst = lkq; col = j - 2 * kE; }
  for (int r = 0; r < ntile; ++r)
    dst[(size_t)(b * kN + n0 + r) * kE + col] =
        enc_fp8((acc[r] + bias) * kFP8Scale);
}

// ---------------------------------------------------------------------------
// Kernel B: qbase[b] = ge@Wfix + bfix + first@Wstep_top + bstep  (fp32)
// ---------------------------------------------------------------------------
__global__ __launch_bounds__(128) void qbase_kernel(
    const float* __restrict__ ne, const float* __restrict__ ge,
    const float* __restrict__ Wfix, const float* __restrict__ bfix,
    const float* __restrict__ Wstep, const float* __restrict__ bstep,
    float* __restrict__ qbase) {
  __shared__ float g[kE], f[kE];
  int b = blockIdx.x, e = threadIdx.x;
  g[e] = ge[b * kE + e];
  f[e] = ne[(size_t)b * kN * kE + e];  // node 0
  __syncthreads();
  float acc = bfix[e] + bstep[e];
  for (int i = 0; i < kE; ++i)
    acc += g[i] * Wfix[i * kE + e] + f[i] * Wstep[i * kE + e];
  qbase[b * kE + e] = acc;
}

// ---------------------------------------------------------------------------
// Kernel B2: qstep[b,n] = (qbase[b] + ne[b,n] @ Wbot) * kQKScale, f16.
// ---------------------------------------------------------------------------
__global__ __launch_bounds__(128) void qstep_kernel(
    const float* __restrict__ ne, const float* __restrict__ Wstep,
    const float* __restrict__ qbase, __half* __restrict__ qstep) {
  __shared__ float rows[8 * kE];
  int b = blockIdx.x;
  int n0 = blockIdx.y * 8;
  int tid = threadIdx.x;
  const float* Wbot = Wstep + kE * kE;

  for (int idx = tid; idx < 8 * kE; idx += 128)
    rows[idx] = ne[((size_t)b * kN + n0) * kE + idx];
  __syncthreads();

  float acc[8];
#pragma unroll
  for (int r = 0; r < 8; ++r) acc[r] = 0.f;
  for (int i = 0; i < kE; ++i) {
    float w = Wbot[i * kE + tid];
#pragma unroll
    for (int r = 0; r < 8; ++r) acc[r] += rows[r * kE + i] * w;
  }
  float qb = qbase[b * kE + tid];
#pragma unroll
  for (int r = 0; r < 8; ++r)
    qstep[((size_t)b * kN + n0 + r) * kE + tid] =
        __float2half((qb + acc[r]) * kQKScale);
}

// ---------------------------------------------------------------------------
// Kernel C: 999-step rollout, one 1024-thread block per batch element.
// Thread (g,t): g = node-group 0..127, t = head / uint4 chunk 0..7.
// Fused scores+ctx phase (p never hits LDS), register prefetch of
// logit_k rows and next q row across LDS-only barriers. 5 barriers/step.
// ---------------------------------------------------------------------------
__global__ __launch_bounds__(1024, 4) void rollout_kernel(
    const float* __restrict__ Wmlp, const float* __restrict__ bmlp,
    const unsigned char* __restrict__ kq, const unsigned char* __restrict__ vq,
    const unsigned char* __restrict__ lkq, const __half* __restrict__ qstep,
    float* __restrict__ out) {
  __shared__ int rem[kN];                 // live node ids
  __shared__ int pos[kN];                 // node id -> position in rem
  __shared__ float ctxp[16][kH][16];      // per-wave ctx partials, 8 KB
  __shared__ float redSum[16][kH];        // per-wave softmax denominators
  __shared__ __align__(16) float ctx[kE];
  __shared__ float bm[kE];
  __shared__ __align__(16) __half xh[kE];
  __shared__ float redM[16], redS[16];
  __shared__ int redI[16];

  int b = blockIdx.x;
  int tid = threadIdx.x;
  int lane = tid & 63;
  int wave = tid >> 6;
  int g = tid >> 3;  // node-group 0..127
  int t = tid & 7;   // head / uint4 slot within row

  const unsigned char* kqb = kq + (size_t)b * kN * kE;
  const unsigned char* vqb = vq + (size_t)b * kN * kE;
  const unsigned char* lqb = lkq + (size_t)b * kN * kE;
  const __half* qsb = qstep + (size_t)b * kN * kE;

  // x-matvec weight column (output elem g, i-chunk t), register resident
  float wm[16];
#pragma unroll
  for (int i = 0; i < 16; ++i) wm[i] = Wmlp[(t * 16 + i) * kE + g];

  for (int i = tid; i < kN - 1; i += 1024) { rem[i] = i + 1; pos[i + 1] = i; }
  if (tid < kE) bm[tid] = bmlp[tid];

  // current action + its q row (prefetched into registers)
  int A = 0;
  uint4 qa, qb_;
  {
    const uint4* qr = (const uint4*)qsb;  // node 0
    qa = qr[2 * t];
    qb_ = qr[2 * t + 1];
  }
  float total = 0.f;

  barrier_lds();  // init (rem/pos/bm) visible

  for (int step = 0; step < kN - 1; ++step) {
    int R = kN - 1 - step;  // live count (deterministic)

    // ================= phase 1: fused scores + ctx partials ==============
    h2 q8[8];
    {
      unsigned qw[8] = {qa.x, qa.y, qa.z, qa.w, qb_.x, qb_.y, qb_.z, qb_.w};
#pragma unroll
      for (int i = 0; i < 8; ++i) q8[i] = __builtin_bit_cast(h2, qw[i]);
    }
    int jn[8];
#pragma unroll
    for (int r = 0; r < 8; ++r) {
      int j = g + 128 * r;
      jn[r] = (j < R) ? rem[j] : -1;
    }
    uint4 ku[8], vu[8];
#pragma unroll
    for (int r = 0; r < 8; ++r)
      if (jn[r] >= 0) {
        ku[r] = ((const uint4*)(kqb + (size_t)jn[r] * kE))[t];
        vu[r] = ((const uint4*)(vqb + (size_t)jn[r] * kE))[t];
      }
    float den = 0.f;
    float acc[16];
#pragma unroll
    for (int i = 0; i < 16; ++i) acc[i] = 0.f;
#pragma unroll
    for (int r = 0; r < 8; ++r)
      if (jn[r] >= 0) {
        float s = dot16(ku[r], q8, 0.f);
        float p = __expf(s);  // scores tiny: no max-subtract
        den += p;
        unsigned uu[4] = {vu[r].x, vu[r].y, vu[r].z, vu[r].w};
#pragma unroll
        for (int c = 0; c < 4; ++c) {
          f2 lo = __builtin_amdgcn_cvt_pk_f32_fp8(uu[c], false);
          f2 hi = __builtin_amdgcn_cvt_pk_f32_fp8(uu[c], true);
          acc[4 * c + 0] += p * lo.x;
          acc[4 * c + 1] += p * lo.y;
          acc[4 * c + 2] += p * hi.x;
          acc[4 * c + 3] += p * hi.y;
        }
      }

    // prefetch logit_k rows for the logits phase (latency hides under the
    // reduce + ctx + x phases; LDS-only barriers keep them in flight)
    uint4 lu[8];
#pragma unroll
    for (int r = 0; r < 8; ++r)
      if (jn[r] >= 0) lu[r] = ((const uint4*)(lqb + (size_t)jn[r] * kE))[t];

    // reduce den/acc over the 8 node-groups of this wave (lanes stride 8)
#pragma unroll
    for (int off = 8; off <= 32; off <<= 1) {
      den += __shfl_xor(den, off);
#pragma unroll
      for (int i = 0; i < 16; ++i) acc[i] += __shfl_xor(acc[i], off);
    }
    if (lane < kH) {  // lane == t for lanes 0..7
      redSum[wave][lane] = den;
#pragma unroll
      for (int i = 0; i < 16; ++i) ctxp[wave][lane][i] = acc[i];
    }
    barrier_lds();  // B_b: ctxp, redSum ready

    // ================= phase 2: finalize ctx =============================
    if (tid < kE) {
      int h = tid >> 4, i = tid & 15;
      float s = 0.f, d2 = 0.f;
#pragma unroll
      for (int w = 0; w < 16; ++w) {
        s += ctxp[w][h][i];
        d2 += redSum[w][h];
      }
      ctx[tid] = s / (d2 * kFP8Scale);
    }
    barrier_lds();  // B_c: ctx ready

    // ================= phase 3: x = (bm + ctx @ Wmlp) * kQKScale =========
    {
      float xacc = 0.f;
      const float4* c4 = (const float4*)(ctx + t * 16);
#pragma unroll
      for (int k4 = 0; k4 < 4; ++k4) {
        float4 cv = c4[k4];
        xacc += cv.x * wm[4 * k4 + 0] + cv.y * wm[4 * k4 + 1] +
                cv.z * wm[4 * k4 + 2] + cv.w * wm[4 * k4 + 3];
      }
      xacc += __shfl_xor(xacc, 1);
      xacc += __shfl_xor(xacc, 2);
      xacc += __shfl_xor(xacc, 4);
      if (t == 0) xh[g] = __float2half((bm[g] + xacc) * kQKScale);
    }
    barrier_lds();  // B_d: xh ready

    // ================= phase 4: logits (lu already in registers) =========
    float m = -1e30f, ssum = 0.f;
    int arg = 0x7fffffff;
    {
      h2 x8[8];
#pragma unroll
      for (int i = 0; i < 8; ++i) x8[i] = ((const h2*)xh)[8 * t + i];
#pragma unroll
      for (int r = 0; r < 8; ++r)
        if (jn[r] >= 0) {
          float s = dot16(lu[r], x8, 0.f);
          s += __shfl_xor(s, 1);
          s += __shfl_xor(s, 2);
          s += __shfl_xor(s, 4);
          if (t == 0) {
            float l = fast_tanh(s) * 10.f;
            combine(m, ssum, arg, l, 1.f, jn[r]);
          }
        }
    }
#pragma unroll
    for (int off = 32; off; off >>= 1) {
      float mo = __shfl_xor(m, off);
      float so = __shfl_xor(ssum, off);
      int ao = __shfl_xor(arg, off);
      combine(m, ssum, arg, mo, so, ao);
    }
    if (lane == 0) { redM[wave] = m; redS[wave] = ssum; redI[wave] = arg; }
    barrier_lds();  // B_e: per-wave reductions ready

    // ====== phase 5: final combine (all threads), q prefetch, update =====
    {
      float M = redM[0], S = redS[0];
      int Af = redI[0];
#pragma unroll
      for (int w = 1; w < 16; ++w) combine(M, S, Af, redM[w], redS[w], redI[w]);
      A = Af;
      total += -logf(S);  // chosen logit == M => log_p[act] = -log S
      // prefetch next q row (every thread knows A; load overlaps barrier)
      const uint4* qr = (const uint4*)(qsb + (size_t)A * kE);
      qa = qr[2 * t];
      qb_ = qr[2 * t + 1];
      if (tid == 0) {  // swap-remove A from live list
        int jp = pos[A];
        int lastn = rem[R - 1];
        rem[jp] = lastn;
        pos[lastn] = jp;
      }
    }
    barrier_lds();  // B_a: rem/pos updated for next step
  }
  if (tid == 0) out[b] = total;
}

// ---------------------------------------------------------------------------
extern "C" void kernel_launch(void* const* d_in, const int* in_sizes, int n_in,
                              void* d_out, int out_size, void* d_ws,
                              size_t ws_size, hipStream_t stream) {
  const float* ne = (const float*)d_in[0];
  const float* ge = (const float*)d_in[1];
  const float* Wqkv = (const float*)d_in[2];
  const float* bqkv = (const float*)d_in[3];
  const float* Wfix = (const float*)d_in[4];
  const float* bfix = (const float*)d_in[5];
  const float* Wstep = (const float*)d_in[6];
  const float* bstep = (const float*)d_in[7];
  const float* Wmlp = (const float*)d_in[8];
  const float* bmlp = (const float*)d_in[9];
  float* out = (float*)d_out;

  size_t nkv = (size_t)kB * kN * kE;  // bytes per fp8 tensor
  unsigned char* kq = (unsigned char*)d_ws;
  unsigned char* vq = kq + nkv;
  unsigned char* lkq = vq + nkv;
  __half* qstep = (__half*)(lkq + nkv);  // 2*nkv bytes
  float* qbase = (float*)(qstep + nkv);  // 64 KB

  qkv_kernel<<<dim3(kB, (kN + 15) / 16), 384, 0, stream>>>(ne, Wqkv, bqkv, kq,
                                                           vq, lkq);
  qbase_kernel<<<kB, kE, 0, stream>>>(ne, ge, Wfix, bfix, Wstep, bstep, qbase);
  qstep_kernel<<<dim3(kB, kN / 8), 128, 0, stream>>>(ne, Wstep, qbase, qstep);
  rollout_kernel<<<kB, 1024, 0, stream>>>(Wmlp, bmlp, kq, vq, lkq, qstep, out);
}

// Round 2
// 12940.161 us; speedup vs baseline: 1.6904x; 1.6904x over previous
//
#include <hip/hip_runtime.h>
#include <hip/hip_fp16.h>

constexpr int kB = 128;
constexpr int kN = 1000;
constexpr int kE = 128;
constexpr int kH = 8;
constexpr float kFP8Scale = 64.f;         // fp8 values stored as v*64
constexpr float kQKScale = 0.25f / 64.f;  // 1/sqrt(16) folded with 1/64
constexpr int kPP = 1028;                 // padded p row stride (floats)

typedef _Float16 h2 __attribute__((ext_vector_type(2)));
typedef float f2 __attribute__((ext_vector_type(2)));

__device__ __forceinline__ h2 pkrtz(float a, float b) {
  return __builtin_bit_cast(h2, __builtin_amdgcn_cvt_pkrtz(a, b));
}

// dot of 4 fp8 elems (packed in u, stored value*64) against 4 f16 elems.
__device__ __forceinline__ float dotq(unsigned u, h2 qa, h2 qb, float s) {
  f2 lo = __builtin_amdgcn_cvt_pk_f32_fp8(u, false);
  f2 hi = __builtin_amdgcn_cvt_pk_f32_fp8(u, true);
  h2 l16 = pkrtz(lo.x, lo.y);
  h2 h16 = pkrtz(hi.x, hi.y);
  s = __builtin_amdgcn_fdot2(l16, qa, s, false);
  s = __builtin_amdgcn_fdot2(h16, qb, s, false);
  return s;
}
// 16-elem fp8 dot (one uint4) against 16 f16 elems in q8[0..7].
__device__ __forceinline__ float dot16(uint4 tq, const h2* q8, float s) {
  s = dotq(tq.x, q8[0], q8[1], s);
  s = dotq(tq.y, q8[2], q8[3], s);
  s = dotq(tq.z, q8[4], q8[5], s);
  s = dotq(tq.w, q8[6], q8[7], s);
  return s;
}

__device__ __forceinline__ float fast_tanh(float x) {
  float t = __expf(2.f * x);
  return 1.f - 2.f / (t + 1.f);
}

__device__ __forceinline__ unsigned char enc_fp8(float v) {
  unsigned p = __builtin_amdgcn_cvt_pk_fp8_f32(v, v, 0, false);
  return (unsigned char)(p & 0xFF);
}

// online-softmax / argmax combine; tie -> smaller node id (jnp.argmax).
__device__ __forceinline__ void combine(float& m, float& s, int& a,
                                        float mo, float so, int ao) {
  bool take = (mo > m) || (mo == m && ao < a);
  float mw = take ? mo : m;
  float ml = take ? m : mo;
  float sw = take ? so : s;
  float sl = take ? s : so;
  s = sw + sl * __expf(ml - mw);
  m = mw;
  a = take ? ao : a;
}

// ---- DPP cross-lane helpers (VALU pipe, not DS) ---------------------------
// ctrl: 0xB1 = quad_perm[1,0,3,2] (xor1), 0x4E = quad_perm[2,3,0,1] (xor2),
// 0x141 = row_half_mirror (xor-equiv across quads within octet),
// 0x128 = row_ror:8 (xor8-equiv within 16-lane row, preserves lane%8).
template <int CTRL>
__device__ __forceinline__ float dpp_bcastf(float x) {
  return __builtin_bit_cast(
      float, __builtin_amdgcn_update_dpp(0, __builtin_bit_cast(int, x), CTRL,
                                         0xf, 0xf, true));
}
template <int CTRL>
__device__ __forceinline__ int dpp_bcasti(int x) {
  return __builtin_amdgcn_update_dpp(0, x, CTRL, 0xf, 0xf, true);
}
template <int CTRL>
__device__ __forceinline__ float dpp_addf(float x) {
  return x + dpp_bcastf<CTRL>(x);
}
template <int CTRL>
__device__ __forceinline__ void dpp_combine(float& m, float& s, int& a) {
  float mo = dpp_bcastf<CTRL>(m);
  float so = dpp_bcastf<CTRL>(s);
  int ao = dpp_bcasti<CTRL>(a);
  combine(m, s, a, mo, so, ao);
}

// LDS-only barrier: drains DS ops, leaves global register-loads in flight.
__device__ __forceinline__ void barrier_lds() {
  asm volatile("s_waitcnt lgkmcnt(0)" ::: "memory");
  __builtin_amdgcn_s_barrier();
  asm volatile("" ::: "memory");
}

// ---------------------------------------------------------------------------
// Kernel A: qkv projection -> fp8 (value*64) k / v / logit_k.
// ---------------------------------------------------------------------------
__global__ __launch_bounds__(384) void qkv_kernel(
    const float* __restrict__ ne, const float* __restrict__ Wqkv,
    const float* __restrict__ bqkv, unsigned char* __restrict__ kq,
    unsigned char* __restrict__ vq, unsigned char* __restrict__ lkq) {
  __shared__ float rows[16 * kE];
  int b = blockIdx.x;
  int n0 = blockIdx.y * 16;
  int ntile = min(16, kN - n0);
  int tid = threadIdx.x;

  for (int idx = tid; idx < ntile * kE; idx += 384)
    rows[idx] = ne[(b * kN + n0) * kE + idx];
  __syncthreads();

  int j = tid;  // 0..383
  float acc[16];
#pragma unroll
  for (int r = 0; r < 16; ++r) acc[r] = 0.f;
  for (int i = 0; i < kE; ++i) {
    float w = Wqkv[i * (3 * kE) + j];
#pragma unroll
    for (int r = 0; r < 16; ++r) acc[r] += rows[r * kE + i] * w;
  }
  float bias = bqkv[j];
  unsigned char* dst;
  int col;
  if (j < kE) { dst = kq; col = j; }
  else if (j < 2 * kE) { dst = vq; col = j - kE; }
  else { dst = lkq; col = j - 2 * kE; }
  for (int r = 0; r < ntile; ++r)
    dst[(size_t)(b * kN + n0 + r) * kE + col] =
        enc_fp8((acc[r] + bias) * kFP8Scale);
}

// ---------------------------------------------------------------------------
// Kernel B: qbase[b] = ge@Wfix + bfix + first@Wstep_top + bstep  (fp32)
// ---------------------------------------------------------------------------
__global__ __launch_bounds__(128) void qbase_kernel(
    const float* __restrict__ ne, const float* __restrict__ ge,
    const float* __restrict__ Wfix, const float* __restrict__ bfix,
    const float* __restrict__ Wstep, const float* __restrict__ bstep,
    float* __restrict__ qbase) {
  __shared__ float g[kE], f[kE];
  int b = blockIdx.x, e = threadIdx.x;
  g[e] = ge[b * kE + e];
  f[e] = ne[(size_t)b * kN * kE + e];  // node 0
  __syncthreads();
  float acc = bfix[e] + bstep[e];
  for (int i = 0; i < kE; ++i)
    acc += g[i] * Wfix[i * kE + e] + f[i] * Wstep[i * kE + e];
  qbase[b * kE + e] = acc;
}

// ---------------------------------------------------------------------------
// Kernel B2: qstep[b,n] = (qbase[b] + ne[b,n] @ Wbot) * kQKScale, f16.
// ---------------------------------------------------------------------------
__global__ __launch_bounds__(128) void qstep_kernel(
    const float* __restrict__ ne, const float* __restrict__ Wstep,
    const float* __restrict__ qbase, __half* __restrict__ qstep) {
  __shared__ float rows[8 * kE];
  int b = blockIdx.x;
  int n0 = blockIdx.y * 8;
  int tid = threadIdx.x;
  const float* Wbot = Wstep + kE * kE;

  for (int idx = tid; idx < 8 * kE; idx += 128)
    rows[idx] = ne[((size_t)b * kN + n0) * kE + idx];
  __syncthreads();

  float acc[8];
#pragma unroll
  for (int r = 0; r < 8; ++r) acc[r] = 0.f;
  for (int i = 0; i < kE; ++i) {
    float w = Wbot[i * kE + tid];
#pragma unroll
    for (int r = 0; r < 8; ++r) acc[r] += rows[r * kE + i] * w;
  }
  float qb = qbase[b * kE + tid];
#pragma unroll
  for (int r = 0; r < 8; ++r)
    qstep[((size_t)b * kN + n0 + r) * kE + tid] =
        __float2half((qb + acc[r]) * kQKScale);
}

// ---------------------------------------------------------------------------
// Kernel C: 999-step rollout, one 1024-thread block per batch element.
// Structure = round-0 proven kernel; changes:
//  * p transposed to [h][j] (pad 1028) -> V phase reads p as float4 broadcast
//  * V phase: 4 contiguous rows per half-wave per q, depth-2 pipeline,
//    first 2 batches issued during the score phase (addresses need only rem)
//  * all xor1/2/4/8 cross-lane reduces via DPP (VALU), shfl only for 16/32
//  * lu prefetched end of V phase; next q row prefetched in registers by all
//    threads (all threads run the 16-entry final combine as a DPP tree)
//  * 6 LDS-only barriers/step (was 7 full barriers)
// ---------------------------------------------------------------------------
__global__ __launch_bounds__(1024) void rollout_kernel(
    const float* __restrict__ Wmlp, const float* __restrict__ bmlp,
    const unsigned char* __restrict__ kq, const unsigned char* __restrict__ vq,
    const unsigned char* __restrict__ lkq, const __half* __restrict__ qstep,
    float* __restrict__ out) {
  __shared__ __align__(16) float p[kH][kPP];  // exp(scores), [h][j], 32.9 KB
  __shared__ __align__(16) int rem[1024];     // live node ids (padded)
  __shared__ int pos[kN];                     // node id -> position in rem
  __shared__ float parts[32 * kE];            // ctx half-wave partials, 16 KB
  __shared__ float bm[kE];
  __shared__ __align__(16) float ctx[kE];
  __shared__ __align__(16) __half xh[kE];
  __shared__ float redSum[16][kH];
  __shared__ __align__(16) float4 redPack[16];  // (m, ssum, argbits, -)

  int b = blockIdx.x;
  int tid = threadIdx.x;
  int lane = tid & 63;
  int wave = tid >> 6;
  int g = tid >> 3;    // node-group 0..127
  int t = tid & 7;     // head / uint4 slot within row
  int w2 = tid >> 5;   // half-wave 0..31
  int idx = tid & 31;  // uint index within a 128B row
  int h = idx >> 2;    // head owning elems 4*idx..4*idx+3

  const unsigned char* kqb = kq + (size_t)b * kN * kE;
  const unsigned char* vqb = vq + (size_t)b * kN * kE;
  const unsigned char* lqb = lkq + (size_t)b * kN * kE;
  const __half* qsb = qstep + (size_t)b * kN * kE;

  // x-matvec weight column (output elem g, i-chunk t), register resident
  float wm[16];
#pragma unroll
  for (int i = 0; i < 16; ++i) wm[i] = Wmlp[(t * 16 + i) * kE + g];

  // init live list (rem padded to 1024 with valid ids for safe prefetch)
  rem[tid] = (tid < kN - 1) ? tid + 1 : 1;
  if (tid < kN - 1) pos[tid + 1] = tid;
  if (tid < kE) bm[tid] = bmlp[tid];

  // current action + its q row (prefetched into registers; node 0 first)
  int A = 0;
  uint4 qa, qb_;
  {
    const uint4* qr = (const uint4*)qsb;
    qa = qr[2 * t];
    qb_ = qr[2 * t + 1];
  }
  float total = 0.f;

  barrier_lds();  // init visible

  for (int step = 0; step < kN - 1; ++step) {
    int R = kN - 1 - step;  // live count (deterministic)

    // ================= phase 1: scores ===================================
    h2 q8[8];
    {
      unsigned qw[8] = {qa.x, qa.y, qa.z, qa.w, qb_.x, qb_.y, qb_.z, qb_.w};
#pragma unroll
      for (int i = 0; i < 8; ++i) q8[i] = __builtin_bit_cast(h2, qw[i]);
    }
    int jn[8];
#pragma unroll
    for (int r = 0; r < 8; ++r) {
      int j = g + 128 * r;
      jn[r] = (j < R) ? rem[j] : -1;
    }
    uint4 ku[8];
#pragma unroll
    for (int r = 0; r < 8; ++r)
      if (jn[r] >= 0) ku[r] = ((const uint4*)(kqb + (size_t)jn[r] * kE))[t];

    // early V prefetch: batches q=0,1 (addresses need only rem; data used in
    // phase 2 — latency hides under the score dots + barrier)
    unsigned uu[2][4];
    int jbv[2];
#pragma unroll
    for (int qq = 0; qq < 2; ++qq) {
      int jb = w2 * 4 + 128 * qq;
      jbv[qq] = jb;
      if (jb < R) {
        int4 rm = *(const int4*)(rem + jb);
        uu[qq][0] = ((const unsigned*)(vqb + (size_t)rm.x * kE))[idx];
        uu[qq][1] = ((const unsigned*)(vqb + (size_t)rm.y * kE))[idx];
        uu[qq][2] = ((const unsigned*)(vqb + (size_t)rm.z * kE))[idx];
        uu[qq][3] = ((const unsigned*)(vqb + (size_t)rm.w * kE))[idx];
      }
    }

    float den = 0.f;
#pragma unroll
    for (int r = 0; r < 8; ++r)
      if (jn[r] >= 0) {
        float s = dot16(ku[r], q8, 0.f);
        float hv = __expf(s);  // scores tiny: no max-subtract
        p[t][g + 128 * r] = hv;
        den += hv;
      }
    // den: sum across the 8 groups of this wave (preserve t = lane%8)
    den = dpp_addf<0x128>(den);   // xor8-equiv
    den += __shfl_xor(den, 16);
    den += __shfl_xor(den, 32);
    if (lane < kH) redSum[wave][lane] = den;  // lane==t for lanes 0..7
    barrier_lds();  // B1: p, redSum ready

    // ================= phase 2: ctx partials =============================
    {
      float a0 = 0.f, a1 = 0.f, a2 = 0.f, a3 = 0.f;
#pragma unroll
      for (int q = 0; q < 8; ++q) {
        const int s = q & 1;
        int jb = jbv[s];
        if (jb < R) {
          float4 pw = *(const float4*)&p[h][jb];
#pragma unroll
          for (int k = 0; k < 4; ++k) {
            if (jb + k < R) {
              unsigned u = uu[s][k];
              float pk = (k == 0) ? pw.x : (k == 1) ? pw.y
                                         : (k == 2) ? pw.z : pw.w;
              f2 lo = __builtin_amdgcn_cvt_pk_f32_fp8(u, false);
              f2 hi = __builtin_amdgcn_cvt_pk_f32_fp8(u, true);
              a0 += pk * lo.x;
              a1 += pk * lo.y;
              a2 += pk * hi.x;
              a3 += pk * hi.y;
            }
          }
        }
        if (q + 2 < 8) {  // issue batch q+2 into slot s (depth-2 pipeline)
          int jb2 = w2 * 4 + 128 * (q + 2);
          jbv[s] = jb2;
          if (jb2 < R) {
            int4 rm = *(const int4*)(rem + jb2);
            uu[s][0] = ((const unsigned*)(vqb + (size_t)rm.x * kE))[idx];
            uu[s][1] = ((const unsigned*)(vqb + (size_t)rm.y * kE))[idx];
            uu[s][2] = ((const unsigned*)(vqb + (size_t)rm.z * kE))[idx];
            uu[s][3] = ((const unsigned*)(vqb + (size_t)rm.w * kE))[idx];
          }
        }
      }
      ((float4*)(parts + w2 * kE))[idx] = make_float4(a0, a1, a2, a3);
    }
    // prefetch logit_k rows (latency hides under ctx + x phases)
    uint4 lu[8];
#pragma unroll
    for (int r = 0; r < 8; ++r)
      if (jn[r] >= 0) lu[r] = ((const uint4*)(lqb + (size_t)jn[r] * kE))[t];
    barrier_lds();  // B2: parts ready

    // ================= phase 3: finalize ctx (128 threads) ===============
    if (tid < kE) {
      int hh = tid >> 4;
      float d2 = 0.f, s = 0.f;
#pragma unroll
      for (int w = 0; w < 16; ++w) d2 += redSum[w][hh];
#pragma unroll
      for (int w = 0; w < 32; ++w) s += parts[w * kE + tid];
      ctx[tid] = s / (d2 * kFP8Scale);
    }
    barrier_lds();  // B3: ctx ready

    // ================= phase 4: x = (bm + ctx @ Wmlp) * kQKScale =========
    {
      float xacc = 0.f;
      const float4* c4 = (const float4*)(ctx + t * 16);
#pragma unroll
      for (int k4 = 0; k4 < 4; ++k4) {
        float4 cv = c4[k4];
        xacc += cv.x * wm[4 * k4 + 0] + cv.y * wm[4 * k4 + 1] +
                cv.z * wm[4 * k4 + 2] + cv.w * wm[4 * k4 + 3];
      }
      xacc = dpp_addf<0xB1>(xacc);   // xor1
      xacc = dpp_addf<0x4E>(xacc);   // xor2
      xacc = dpp_addf<0x141>(xacc);  // xor4-equiv (octet mirror)
      if (t == 0) xh[g] = __float2half((bm[g] + xacc) * kQKScale);
    }
    barrier_lds();  // B4: xh ready

    // ================= phase 5: logits (lu already in registers) =========
    float m = -1e30f, ssum = 0.f;
    int arg = 0x7fffffff;
    {
      h2 x8[8];
      uint4 xv0 = ((const uint4*)xh)[2 * t];
      uint4 xv1 = ((const uint4*)xh)[2 * t + 1];
      unsigned xw[8] = {xv0.x, xv0.y, xv0.z, xv0.w,
                        xv1.x, xv1.y, xv1.z, xv1.w};
#pragma unroll
      for (int i = 0; i < 8; ++i) x8[i] = __builtin_bit_cast(h2, xw[i]);
#pragma unroll
      for (int r = 0; r < 8; ++r)
        if (jn[r] >= 0) {  // uniform within each 8-lane octet (depends on g)
          float s = dot16(lu[r], x8, 0.f);
          s = dpp_addf<0xB1>(s);
          s = dpp_addf<0x4E>(s);
          s = dpp_addf<0x141>(s);
          if (t == 0) {
            float l = fast_tanh(s) * 10.f;
            combine(m, ssum, arg, l, 1.f, jn[r]);
          }
        }
    }
    // wave butterfly: DPP for 1/2/4/8, shfl for 16/32
    dpp_combine<0xB1>(m, ssum, arg);
    dpp_combine<0x4E>(m, ssum, arg);
    dpp_combine<0x141>(m, ssum, arg);
    dpp_combine<0x128>(m, ssum, arg);
#pragma unroll
    for (int off = 16; off <= 32; off <<= 1) {
      float mo = __shfl_xor(m, off);
      float so = __shfl_xor(ssum, off);
      int ao = __shfl_xor(arg, off);
      combine(m, ssum, arg, mo, so, ao);
    }
    if (lane == 0)
      redPack[wave] = make_float4(m, ssum, __int_as_float(arg), 0.f);
    barrier_lds();  // B5: per-wave reductions ready

    // ====== phase 6: all-thread final combine (DPP tree), q prefetch =====
    {
      float4 rp = redPack[lane & 15];
      float M = rp.x, S = rp.y;
      int Af = __float_as_int(rp.z);
      dpp_combine<0xB1>(M, S, Af);
      dpp_combine<0x4E>(M, S, Af);
      dpp_combine<0x141>(M, S, Af);
      dpp_combine<0x128>(M, S, Af);
      A = Af;
      total += -logf(S);  // chosen logit == M => log_p[act] = -log S
      // prefetch next q row (every thread knows A; load overlaps barrier)
      const uint4* qr = (const uint4*)(qsb + (size_t)A * kE);
      qa = qr[2 * t];
      qb_ = qr[2 * t + 1];
      if (tid == 0) {  // swap-remove A from live list
        int jp = pos[A];
        int lastn = rem[R - 1];
        rem[jp] = lastn;
        pos[lastn] = jp;
      }
    }
    barrier_lds();  // B6: rem/pos updated for next step
  }
  if (tid == 0) out[b] = total;
}

// ---------------------------------------------------------------------------
extern "C" void kernel_launch(void* const* d_in, const int* in_sizes, int n_in,
                              void* d_out, int out_size, void* d_ws,
                              size_t ws_size, hipStream_t stream) {
  const float* ne = (const float*)d_in[0];
  const float* ge = (const float*)d_in[1];
  const float* Wqkv = (const float*)d_in[2];
  const float* bqkv = (const float*)d_in[3];
  const float* Wfix = (const float*)d_in[4];
  const float* bfix = (const float*)d_in[5];
  const float* Wstep = (const float*)d_in[6];
  const float* bstep = (const float*)d_in[7];
  const float* Wmlp = (const float*)d_in[8];
  const float* bmlp = (const float*)d_in[9];
  float* out = (float*)d_out;

  size_t nkv = (size_t)kB * kN * kE;  // bytes per fp8 tensor
  unsigned char* kq = (unsigned char*)d_ws;
  unsigned char* vq = kq + nkv;
  unsigned char* lkq = vq + nkv;
  __half* qstep = (__half*)(lkq + nkv);  // 2*nkv bytes
  float* qbase = (float*)(qstep + nkv);  // 64 KB

  qkv_kernel<<<dim3(kB, (kN + 15) / 16), 384, 0, stream>>>(ne, Wqkv, bqkv, kq,
                                                           vq, lkq);
  qbase_kernel<<<kB, kE, 0, stream>>>(ne, ge, Wfix, bfix, Wstep, bstep, qbase);
  qstep_kernel<<<dim3(kB, kN / 8), 128, 0, stream>>>(ne, Wstep, qbase, qstep);
  rollout_kernel<<<kB, 1024, 0, stream>>>(Wmlp, bmlp, kq, vq, lkq, qstep, out);
}